// Round 7
// baseline (1127.144 us; speedup 1.0000x reference)
//
#include <hip/hip_runtime.h>
#include <math.h>

#define NN 2048
#define BATCH 32
#define COLS 64            // 32 sin cols + 32 cos cols
#define DT_STEP 0.1f
#define NSTEPS 10
#define JS 32              // j-splits
#define JR 64              // NN/JS
#define RB 16              // row blocks of 128 rows
#define GRID_SZ (JS * RB)  // 512 blocks = 2 blocks/CU

// ---------------------------------------------------------------------------
// async global->LDS (16B/lane). LDS dest wave-uniform base + lane*16;
// global src per-lane. [guide m03/m97/m104]
// ---------------------------------------------------------------------------
#if defined(__has_builtin)
#if __has_builtin(__builtin_amdgcn_global_load_lds)
#define HAVE_GLOBAL_LOAD_LDS 1
#endif
#endif

__device__ __forceinline__ void async_copy16(const float* g, float* l) {
#ifdef HAVE_GLOBAL_LOAD_LDS
    __builtin_amdgcn_global_load_lds(
        (const __attribute__((address_space(1))) void*)g,
        (__attribute__((address_space(3))) void*)l, 16, 0, 0);
#else
    int lane = threadIdx.x & 63;
    *(float4*)(l + lane * 4) = *(const float4*)(g);
#endif
}

// ---------------------------------------------------------------------------
// init: theta copy + X0[j][col]: sin/cos; zero split-K counters
// ---------------------------------------------------------------------------
__global__ __launch_bounds__(256) void init_kernel(const float* __restrict__ theta_in,
                                                   float* __restrict__ theta,
                                                   float* __restrict__ X0,
                                                   int* __restrict__ counters) {
    int t = blockIdx.x * 256 + threadIdx.x;
    int b = t >> 11;
    int i = t & (NN - 1);
    float th = theta_in[t];
    theta[t] = th;
    X0[(size_t)i * COLS + b]      = sinf(th);
    X0[(size_t)i * COLS + 32 + b] = cosf(th);
    if (t < NSTEPS * RB) counters[t] = 0;
}

#define FMA4(A, S, V)                      \
    A.x = fmaf(S, V.x, A.x);               \
    A.y = fmaf(S, V.y, A.y);               \
    A.z = fmaf(S, V.z, A.z);               \
    A.w = fmaf(S, V.w, A.w);

// ---------------------------------------------------------------------------
// fused step: split-K GEMM (P[s][c][i] = sum_{j in s} K[i][j]*Xin[j][c])
// + last-block-per-rowblock Kuramoto update (round-4 fence pattern).
// block (s,rb): 128 rows x 64 cols x 64 j. Thread tile 8x4.
// K-tile (32KB) + X-slab (16KB) async-staged to LDS; compute LDS-only.
// NOTE: plain __launch_bounds__(256) — (256,4) collapsed VGPRs to 32 in r4.
// ---------------------------------------------------------------------------
__global__ __launch_bounds__(256) void step_kernel(const float* __restrict__ K,
                                                   const float* __restrict__ Xin,
                                                   float* __restrict__ Xout,
                                                   float* __restrict__ P,
                                                   float* __restrict__ theta,
                                                   const float* __restrict__ omega,
                                                   const float* __restrict__ Kg,
                                                   const float* __restrict__ mu,
                                                   int* __restrict__ counter) {
    __shared__ float smem[12288];            // 48 KB
    float* Klds = smem;                      // [128][64] = 32 KB
    float* Xs   = smem + 8192;               // [64][64]  = 16 KB
    __shared__ int isLast;

    const int tid = threadIdx.x;
    const int bid = blockIdx.x;
    const int s  = bid >> 4;                 // 0..31
    const int rb = bid & 15;                 // 0..15 (rb%8 XCD-stable)
    const int w  = tid >> 6;                 // wave 0..3
    const int ln = tid & 63;
    const int cg = tid & 15;
    const int rg = tid >> 4;                 // 0..15
    const int c0 = cg * 4;
    const int j0 = s * JR;

    // ---- async stage K-tile: 128 rows x 64 j. 1 instr = 4 rows (1 KB).
    {
        const float* Kgp = K + (size_t)rb * 128 * NN + j0;
        const int rsub = ln >> 4;            // 0..3 row within quad
        const int col4 = (ln & 15) * 4;      // 0..60
#pragma unroll
        for (int u = 0; u < 8; ++u) {
            const int r0 = u * 16 + w * 4;   // wave-uniform
            async_copy16(Kgp + (size_t)(r0 + rsub) * NN + col4,
                         Klds + r0 * JR);
        }
    }
    // ---- async stage X-slab: 64 j x 64 c contiguous (16 KB).
    {
        const float* Xg = Xin + (size_t)j0 * COLS;
#pragma unroll
        for (int u = 0; u < 4; ++u) {
            const int base = u * 1024 + w * 256;   // wave-uniform
            async_copy16(Xg + base + ln * 4, Xs + base);
        }
    }
    __syncthreads();   // drains vmcnt(0): staged data visible

    // ---- compute: thread tile 8 rows x 4 cols over 64 j
    const float* KpL = Klds + (size_t)(rg * 8) * JR;

    float4 acc[8];
#pragma unroll
    for (int r = 0; r < 8; ++r) acc[r] = (float4){0.f, 0.f, 0.f, 0.f};

#pragma unroll 4
    for (int j = 0; j < JR; j += 4) {
        float4 xv0 = *(const float4*)(Xs + (size_t)(j + 0) * COLS + c0);
        float4 xv1 = *(const float4*)(Xs + (size_t)(j + 1) * COLS + c0);
        float4 xv2 = *(const float4*)(Xs + (size_t)(j + 2) * COLS + c0);
        float4 xv3 = *(const float4*)(Xs + (size_t)(j + 3) * COLS + c0);
#pragma unroll
        for (int r = 0; r < 8; ++r) {
            float4 kr = *(const float4*)(KpL + (size_t)r * JR + j);
            FMA4(acc[r], kr.x, xv0)
            FMA4(acc[r], kr.y, xv1)
            FMA4(acc[r], kr.z, xv2)
            FMA4(acc[r], kr.w, xv3)
        }
    }

    // ---- transposed (coalesced) P store; T overlays staging region
    __syncthreads();                         // all LDS reads done
    float (*T)[65] = (float (*)[65])smem;    // 128x65 = 33.3 KB < 48 KB
    const int lr = rg * 8;
#pragma unroll
    for (int r = 0; r < 8; ++r)
        *(float4*)&T[lr + r][c0] = acc[r];
    __syncthreads();

    {
        const int io   = tid & 127;          // row within 128-row tile
        const int cgrp = tid >> 7;           // 0..1 -> 32-col halves
        float* Pb = P + ((size_t)s * COLS + cgrp * 32) * NN
                      + (size_t)rb * 128 + io;
#pragma unroll
        for (int cc = 0; cc < 32; ++cc)
            Pb[(size_t)cc * NN] = T[io][cgrp * 32 + cc];
    }

    // ---- split-K completion: last block for this row-block updates it
    __syncthreads();                         // vmcnt(0) drained before barrier
    if (tid == 0) {
        __threadfence();                     // release P stores
        int old = atomicAdd(counter + rb, 1);
        isLast = (old == JS - 1) ? 1 : 0;
    }
    __syncthreads();
    if (!isLast) return;
    __threadfence();                         // acquire

    // update rows rb*128..+127, all 32 batches: 4096 elems, 16/thread
    const float g = (Kg[0] / (float)NN) * (mu[0] * 0.5f);
#pragma unroll
    for (int it = 0; it < 16; ++it) {
        int e  = it * 256 + tid;
        int il = e & 127;
        int b  = e >> 7;
        int i  = rb * 128 + il;

        float sA = 0.f, sB = 0.f, cA = 0.f, cB = 0.f;
#pragma unroll 8
        for (int ss = 0; ss < JS; ss += 2) {
            sA += P[((size_t)(ss + 0) * COLS + b) * NN + i];
            sB += P[((size_t)(ss + 1) * COLS + b) * NN + i];
            cA += P[((size_t)(ss + 0) * COLS + 32 + b) * NN + i];
            cB += P[((size_t)(ss + 1) * COLS + 32 + b) * NN + i];
        }
        float sumS = sA + sB;
        float sumC = cA + cB;

        float th = theta[(size_t)b * NN + i];
        float sV = sinf(th);                 // == Xin value (same fn, same input)
        float cV = cosf(th);

        float dth = omega[i] + g * (cV * sumS - sV * sumC);
        float thn = th + DT_STEP * dth;
        float sn = sinf(thn);
        float cn = cosf(thn);
        theta[(size_t)b * NN + i] = atan2f(sn, cn);
        Xout[(size_t)i * COLS + b]      = sn;
        Xout[(size_t)i * COLS + 32 + b] = cn;
    }
}

// ---------------------------------------------------------------------------
// coherence
// ---------------------------------------------------------------------------
__global__ __launch_bounds__(256) void coh_kernel(const float* __restrict__ theta,
                                                  float* __restrict__ out) {
    int b = blockIdx.x;
    const float* th = theta + (size_t)b * NN;
    float sc = 0.f, ss = 0.f;
    for (int i = threadIdx.x; i < NN; i += 256) {
        float t = th[i];
        sc += cosf(t);
        ss += sinf(t);
    }
    for (int off = 32; off > 0; off >>= 1) {
        sc += __shfl_down(sc, off);
        ss += __shfl_down(ss, off);
    }
    __shared__ float red[2][4];
    int wave = threadIdx.x >> 6;
    if ((threadIdx.x & 63) == 0) { red[0][wave] = sc; red[1][wave] = ss; }
    __syncthreads();
    if (threadIdx.x == 0) {
        float csum = red[0][0] + red[0][1] + red[0][2] + red[0][3];
        float ssum = red[1][0] + red[1][1] + red[1][2] + red[1][3];
        float cm = csum / (float)NN;
        float sm = ssum / (float)NN;
        out[b] = sqrtf(cm * cm + sm * sm);
    }
}

extern "C" void kernel_launch(void* const* d_in, const int* in_sizes, int n_in,
                              void* d_out, int out_size, void* d_ws, size_t ws_size,
                              hipStream_t stream) {
    const float* theta0 = (const float*)d_in[0];
    const float* K      = (const float*)d_in[1];
    const float* omega  = (const float*)d_in[2];
    const float* Kg     = (const float*)d_in[3];
    const float* mu     = (const float*)d_in[4];

    float* out   = (float*)d_out;
    float* theta = out;                 // BATCH*NN
    float* coh   = out + BATCH * NN;    // BATCH

    float* X0 = (float*)d_ws;                           // NN x COLS (512 KB)
    float* X1 = X0 + (size_t)NN * COLS;                 // NN x COLS (512 KB)
    float* P  = X1 + (size_t)NN * COLS;                 // JS x COLS x NN (16.8 MB)
    int* counters = (int*)(P + (size_t)JS * COLS * NN); // NSTEPS x RB ints

    init_kernel<<<(BATCH * NN) / 256, 256, 0, stream>>>(theta0, theta, X0, counters);
    for (int step = 0; step < NSTEPS; ++step) {
        const float* xin = (step & 1) ? X1 : X0;
        float*       xout = (step & 1) ? X0 : X1;
        step_kernel<<<GRID_SZ, 256, 0, stream>>>(K, xin, xout, P, theta, omega,
                                                 Kg, mu, counters + step * RB);
    }
    coh_kernel<<<BATCH, 256, 0, stream>>>(theta, coh);
}

// Round 9
// 280.589 us; speedup vs baseline: 4.0171x; 4.0171x over previous
//
#include <hip/hip_runtime.h>
#include <math.h>

#define NN 2048
#define BATCH 32
#define COLS 64            // 32 sin cols + 32 cos cols
#define DT_STEP 0.1f
#define NSTEPS 10
#define JS 16              // j-splits
#define JR 128             // NN/JS
#define RB 32              // row blocks of 64 rows
#define GRID_SZ (JS * RB)  // 512 blocks = 2 blocks/CU
#define UPD_I 16           // i-rows per update block
#define UPD_GRID (NN / UPD_I)   // 128 blocks

// ---------------------------------------------------------------------------
// async global->LDS (16B/lane). LDS dest wave-uniform base + lane*16;
// global src per-lane. [guide m03/m97/m104]
// ---------------------------------------------------------------------------
#if defined(__has_builtin)
#if __has_builtin(__builtin_amdgcn_global_load_lds)
#define HAVE_GLOBAL_LOAD_LDS 1
#endif
#endif

__device__ __forceinline__ void async_copy16(const float* g, float* l) {
#ifdef HAVE_GLOBAL_LOAD_LDS
    __builtin_amdgcn_global_load_lds(
        (const __attribute__((address_space(1))) void*)g,
        (__attribute__((address_space(3))) void*)l, 16, 0, 0);
#else
    int lane = threadIdx.x & 63;
    *(float4*)(l + lane * 4) = *(const float4*)(g);
#endif
}

// ---------------------------------------------------------------------------
// init: theta copy + X[j][col]: X[j][b]=sin, X[j][32+b]=cos
// ---------------------------------------------------------------------------
__global__ __launch_bounds__(256) void init_kernel(const float* __restrict__ theta_in,
                                                   float* __restrict__ theta,
                                                   float* __restrict__ X) {
    int t = blockIdx.x * 256 + threadIdx.x;
    int b = t >> 11;
    int i = t & (NN - 1);
    float th = theta_in[t];
    theta[t] = th;
    X[(size_t)i * COLS + b]      = sinf(th);
    X[(size_t)i * COLS + 32 + b] = cosf(th);
}

#define FMA4(A, S, V)                      \
    A.x = fmaf(S, V.x, A.x);               \
    A.y = fmaf(S, V.y, A.y);               \
    A.z = fmaf(S, V.z, A.z);               \
    A.w = fmaf(S, V.w, A.w);

// ---------------------------------------------------------------------------
// GEMM: P[s][i][c] = sum_{j in split s} K[i][j] * X[j][c]   (gemm-natural!)
// block (s,rb): 64 rows x 64 cols x 128 j; K-tile + X-slab async-staged to
// LDS; compute LDS-only; epilogue = 4 coalesced float4 stores (no transpose,
// no extra barriers — transpose moved to the update kernel).
// NOTE: plain __launch_bounds__(256) — (256,4) collapsed VGPRs to 32 in r4.
// ---------------------------------------------------------------------------
__global__ __launch_bounds__(256) void gemm_step_kernel(const float* __restrict__ K,
                                                        const float* __restrict__ X,
                                                        float* __restrict__ P) {
    __shared__ float smem[16384];            // 64 KB
    float* Klds = smem;                      // [64][128] = 32 KB
    float* Xs   = smem + 8192;               // [128][64] = 32 KB

    const int tid = threadIdx.x;
    const int bid = blockIdx.x;
    const int s  = bid >> 5;
    const int rb = bid & 31;                 // bid%8 = rb%8: XCD-stable rows
    const int w  = tid >> 6;                 // wave 0..3
    const int ln = tid & 63;
    const int cg = tid & 15;
    const int rg = tid >> 4;                 // 0..15
    const int c0 = cg * 4;
    const int rowBase = rb * 64 + rg * 4;
    const int j0 = s * JR;

    // ---- async stage K-tile: 64 rows x 128 j. Per instr: 2 rows (1 KB).
    {
        const float* Kg = K + (size_t)rb * 64 * NN + j0;
        const int sub = ln >> 5;             // 0/1: which row of the pair
        const int col4 = (ln & 31) * 4;      // 0..124
#pragma unroll
        for (int u = 0; u < 8; ++u) {
            const int r0 = u * 8 + w * 2;    // wave-uniform row pair base
            async_copy16(Kg + (size_t)(r0 + sub) * NN + col4,
                         Klds + r0 * JR);
        }
    }
    // ---- async stage X-slab: 128 j x 64 c, contiguous 32 KB.
    {
        const float* Xg = X + (size_t)j0 * COLS;
#pragma unroll
        for (int u = 0; u < 8; ++u) {
            const int base = u * 1024 + w * 256;   // wave-uniform
            async_copy16(Xg + base + ln * 4, Xs + base);
        }
    }
    __syncthreads();   // drains vmcnt(0): all staged data visible

    // ---- compute from LDS: 4x4 thread tile over 128 j
    const float* KpL = Klds + (size_t)(rg * 4) * JR;

    float4 acc0 = {0.f,0.f,0.f,0.f}, acc1 = {0.f,0.f,0.f,0.f};
    float4 acc2 = {0.f,0.f,0.f,0.f}, acc3 = {0.f,0.f,0.f,0.f};

#pragma unroll 8
    for (int j = 0; j < JR; j += 4) {
        float4 xv0 = *(const float4*)(Xs + (size_t)(j + 0) * COLS + c0);
        float4 xv1 = *(const float4*)(Xs + (size_t)(j + 1) * COLS + c0);
        float4 xv2 = *(const float4*)(Xs + (size_t)(j + 2) * COLS + c0);
        float4 xv3 = *(const float4*)(Xs + (size_t)(j + 3) * COLS + c0);
        float4 k0 = *(const float4*)(KpL + 0 * JR + j);
        float4 k1 = *(const float4*)(KpL + 1 * JR + j);
        float4 k2 = *(const float4*)(KpL + 2 * JR + j);
        float4 k3 = *(const float4*)(KpL + 3 * JR + j);

        FMA4(acc0, k0.x, xv0) FMA4(acc0, k0.y, xv1) FMA4(acc0, k0.z, xv2) FMA4(acc0, k0.w, xv3)
        FMA4(acc1, k1.x, xv0) FMA4(acc1, k1.y, xv1) FMA4(acc1, k1.z, xv2) FMA4(acc1, k1.w, xv3)
        FMA4(acc2, k2.x, xv0) FMA4(acc2, k2.y, xv1) FMA4(acc2, k2.z, xv2) FMA4(acc2, k2.w, xv3)
        FMA4(acc3, k3.x, xv0) FMA4(acc3, k3.y, xv1) FMA4(acc3, k3.z, xv2) FMA4(acc3, k3.w, xv3)
    }

    // ---- direct coalesced epilogue: P[s][rowBase+r][c0..c0+3]
    float* Pb = P + ((size_t)s * NN + rowBase) * COLS + c0;
    *(float4*)(Pb + 0 * COLS) = acc0;
    *(float4*)(Pb + 1 * COLS) = acc1;
    *(float4*)(Pb + 2 * COLS) = acc2;
    *(float4*)(Pb + 3 * COLS) = acc3;
}

// ---------------------------------------------------------------------------
// update (two-phase): block owns UPD_I=16 i-rows.
// Phase 1: sum_s P[s][i][c] with coalesced float4 reads, acc in registers,
//          one ds_write_b128 into padded Ts.
// Phase 2: thread (b,i) gathers Ts[i][b], Ts[i][32+b], applies Kuramoto
//          step, wraps, refreshes X.
// ---------------------------------------------------------------------------
__global__ __launch_bounds__(256) void update_step_kernel(float* __restrict__ theta,
                                                          float* __restrict__ X,
                                                          const float* __restrict__ P,
                                                          const float* __restrict__ omega,
                                                          const float* __restrict__ Kg,
                                                          const float* __restrict__ mu) {
    __shared__ float Ts[UPD_I][68];          // stride 68: 16B-aligned rows, <=2-way banks

    const int tid = threadIdx.x;
    const int iBase = blockIdx.x * UPD_I;

    // ---- phase 1: thread -> (i_local = tid>>4, c-quad = tid&15)
    {
        const int il = tid >> 4;             // 0..15
        const int c4 = (tid & 15) * 4;       // 0..60
        const float* Pp = P + ((size_t)iBase + il) * COLS + c4;
        float4 a = {0.f, 0.f, 0.f, 0.f};
#pragma unroll
        for (int ss = 0; ss < JS; ++ss) {
            float4 v = *(const float4*)(Pp + (size_t)ss * NN * COLS);
            a.x += v.x; a.y += v.y; a.z += v.z; a.w += v.w;
        }
        *(float4*)&Ts[il][c4] = a;
    }
    __syncthreads();

    // ---- phase 2: thread -> (il = tid&15, b = tid>>4 and +16)
    const float g = (Kg[0] / (float)NN) * (mu[0] * 0.5f);
    const int il = tid & 15;
    const int b0 = tid >> 4;                 // 0..15
    const int i  = iBase + il;
    const float om = omega[i];
#pragma unroll
    for (int k = 0; k < 2; ++k) {
        const int b = b0 + k * 16;
        float sumS = Ts[il][b];
        float sumC = Ts[il][32 + b];
        float th = theta[(size_t)b * NN + i];
        float sV = X[(size_t)i * COLS + b];
        float cV = X[(size_t)i * COLS + 32 + b];

        float dth = om + g * (cV * sumS - sV * sumC);
        float thn = th + DT_STEP * dth;
        float sn = sinf(thn);
        float cn = cosf(thn);
        theta[(size_t)b * NN + i] = atan2f(sn, cn);
        X[(size_t)i * COLS + b]      = sn;
        X[(size_t)i * COLS + 32 + b] = cn;
    }
}

// ---------------------------------------------------------------------------
// coherence
// ---------------------------------------------------------------------------
__global__ __launch_bounds__(256) void coh_kernel(const float* __restrict__ theta,
                                                  float* __restrict__ out) {
    int b = blockIdx.x;
    const float* th = theta + (size_t)b * NN;
    float sc = 0.f, ss = 0.f;
    for (int i = threadIdx.x; i < NN; i += 256) {
        float t = th[i];
        sc += cosf(t);
        ss += sinf(t);
    }
    for (int off = 32; off > 0; off >>= 1) {
        sc += __shfl_down(sc, off);
        ss += __shfl_down(ss, off);
    }
    __shared__ float red[2][4];
    int wave = threadIdx.x >> 6;
    if ((threadIdx.x & 63) == 0) { red[0][wave] = sc; red[1][wave] = ss; }
    __syncthreads();
    if (threadIdx.x == 0) {
        float csum = red[0][0] + red[0][1] + red[0][2] + red[0][3];
        float ssum = red[1][0] + red[1][1] + red[1][2] + red[1][3];
        float cm = csum / (float)NN;
        float sm = ssum / (float)NN;
        out[b] = sqrtf(cm * cm + sm * sm);
    }
}

extern "C" void kernel_launch(void* const* d_in, const int* in_sizes, int n_in,
                              void* d_out, int out_size, void* d_ws, size_t ws_size,
                              hipStream_t stream) {
    const float* theta0 = (const float*)d_in[0];
    const float* K      = (const float*)d_in[1];
    const float* omega  = (const float*)d_in[2];
    const float* Kg     = (const float*)d_in[3];
    const float* mu     = (const float*)d_in[4];

    float* out   = (float*)d_out;
    float* theta = out;                 // BATCH*NN
    float* coh   = out + BATCH * NN;    // BATCH

    float* X = (float*)d_ws;                       // NN x COLS      (512 KB)
    float* P = X + (size_t)NN * COLS;              // JS x NN x COLS (8.4 MB)

    init_kernel<<<(BATCH * NN) / 256, 256, 0, stream>>>(theta0, theta, X);
    for (int step = 0; step < NSTEPS; ++step) {
        gemm_step_kernel<<<GRID_SZ, 256, 0, stream>>>(K, X, P);
        update_step_kernel<<<UPD_GRID, 256, 0, stream>>>(theta, X, P, omega, Kg, mu);
    }
    coh_kernel<<<BATCH, 256, 0, stream>>>(theta, coh);
}

// Round 10
// 218.565 us; speedup vs baseline: 5.1570x; 1.2838x over previous
//
#include <hip/hip_runtime.h>
#include <math.h>

#define NN 2048
#define BATCH 32
#define COLS 64            // 32 sin cols + 32 cos cols
#define DT_STEP 0.1f
#define NSTEPS 10
#define JS 16              // k-splits
#define KR 128             // NN/JS k-range per split
#define GRID_SZ (JS * 32)  // 512 blocks: (s, rb)
#define UPD_I 16           // i-rows per update block
#define UPD_GRID (NN / UPD_I)   // 128 blocks

typedef __attribute__((ext_vector_type(8))) short bf16x8;   // 8 bf16 (4 VGPRs)
typedef __attribute__((ext_vector_type(4))) float f32x4;

// RNE float -> bf16
__device__ __forceinline__ unsigned short f2bf(float f) {
    unsigned int u = __float_as_uint(f);
    u += 0x7FFFu + ((u >> 16) & 1u);
    return (unsigned short)(u >> 16);
}
__device__ __forceinline__ unsigned int pk2(float a, float b) {
    return (unsigned int)f2bf(a) | ((unsigned int)f2bf(b) << 16);
}

// ---------------------------------------------------------------------------
// prep: K fp32 -> bf16 (RNE, every call: ws is re-poisoned), theta copy,
// Xt[c][j] bf16 init (c<32: sin(theta[c][j]); c>=32: cos(theta[c-32][j])).
// grid 2048x256: thread t converts K[8t..8t+7]; t < BATCH*NN also does theta/Xt.
// ---------------------------------------------------------------------------
__global__ __launch_bounds__(256) void prep_kernel(const float* __restrict__ theta_in,
                                                   const float* __restrict__ K,
                                                   float* __restrict__ theta,
                                                   unsigned short* __restrict__ Xt,
                                                   unsigned short* __restrict__ Kb) {
    int t = blockIdx.x * 256 + threadIdx.x;          // 0 .. 524287
    {
        const float4* K4 = (const float4*)K;
        float4 v0 = K4[2 * t];
        float4 v1 = K4[2 * t + 1];
        uint4 o;
        o.x = pk2(v0.x, v0.y);
        o.y = pk2(v0.z, v0.w);
        o.z = pk2(v1.x, v1.y);
        o.w = pk2(v1.z, v1.w);
        ((uint4*)Kb)[t] = o;
    }
    if (t < BATCH * NN) {
        int b = t >> 11;
        int i = t & (NN - 1);
        float th = theta_in[t];
        theta[t] = th;
        Xt[(size_t)b * NN + i]        = f2bf(sinf(th));
        Xt[(size_t)(32 + b) * NN + i] = f2bf(cosf(th));
    }
}

// ---------------------------------------------------------------------------
// MFMA GEMM: P[s][i][c] = sum_{k in split s} K[i][k] * X[k][c]
// block (s, rb): 4 waves; wave w: rows rb*64+w*16 .. +15, all 64 cols,
// k-range 128 (4 chunks of 32). No LDS, no barriers.
// A frag: lane l, elem e -> K[rowBase + (l&15)][k0 + kc*32 + (l>>4)*8 + e]
// B frag: lane l, elem e -> Xt[n*16 + (l&15)][k0 + kc*32 + (l>>4)*8 + e]
// D: row = (l>>4)*4 + r, col = l&15   [HW-verified mapping]
// ---------------------------------------------------------------------------
__global__ __launch_bounds__(256) void gemm_mfma_kernel(const unsigned short* __restrict__ Kb,
                                                        const unsigned short* __restrict__ Xt,
                                                        float* __restrict__ P) {
    const int tid = threadIdx.x;
    const int bid = blockIdx.x;
    const int s  = bid >> 5;                 // 0..15
    const int rb = bid & 31;                 // bid%8 stable: XCD-friendly
    const int w  = tid >> 6;
    const int l  = tid & 63;
    const int lr = l & 15;
    const int lk = l >> 4;                   // 0..3
    const int k0 = s * KR;
    const int rowBase = rb * 64 + w * 16;

    const unsigned short* Ap = Kb + (size_t)(rowBase + lr) * NN + k0 + lk * 8;
    const unsigned short* Bp = Xt + (size_t)lr * NN + k0 + lk * 8;

    f32x4 acc0 = {0.f, 0.f, 0.f, 0.f};
    f32x4 acc1 = {0.f, 0.f, 0.f, 0.f};
    f32x4 acc2 = {0.f, 0.f, 0.f, 0.f};
    f32x4 acc3 = {0.f, 0.f, 0.f, 0.f};

#pragma unroll
    for (int kc = 0; kc < 4; ++kc) {
        bf16x8 a  = *(const bf16x8*)(Ap + kc * 32);
        bf16x8 b0 = *(const bf16x8*)(Bp + (size_t)0 * 16 * NN + kc * 32);
        bf16x8 b1 = *(const bf16x8*)(Bp + (size_t)1 * 16 * NN + kc * 32);
        bf16x8 b2 = *(const bf16x8*)(Bp + (size_t)2 * 16 * NN + kc * 32);
        bf16x8 b3 = *(const bf16x8*)(Bp + (size_t)3 * 16 * NN + kc * 32);
        acc0 = __builtin_amdgcn_mfma_f32_16x16x32_bf16(a, b0, acc0, 0, 0, 0);
        acc1 = __builtin_amdgcn_mfma_f32_16x16x32_bf16(a, b1, acc1, 0, 0, 0);
        acc2 = __builtin_amdgcn_mfma_f32_16x16x32_bf16(a, b2, acc2, 0, 0, 0);
        acc3 = __builtin_amdgcn_mfma_f32_16x16x32_bf16(a, b3, acc3, 0, 0, 0);
    }

    // store: P[s][rowBase + lk*4 + r][n*16 + lr]
    float* Pb = P + ((size_t)s * NN + rowBase + lk * 4) * COLS + lr;
#pragma unroll
    for (int r = 0; r < 4; ++r) {
        Pb[(size_t)r * COLS +  0] = acc0[r];
        Pb[(size_t)r * COLS + 16] = acc1[r];
        Pb[(size_t)r * COLS + 32] = acc2[r];
        Pb[(size_t)r * COLS + 48] = acc3[r];
    }
}

// ---------------------------------------------------------------------------
// update (two-phase): block owns UPD_I=16 i-rows.
// Phase 1: sum_s P[s][i][c], coalesced float4 reads, ds_write into padded Ts.
// Phase 2: thread (b,i): Kuramoto step (sV/cV recomputed fp32), wrap,
//          write Xt bf16.
// ---------------------------------------------------------------------------
__global__ __launch_bounds__(256) void update_step_kernel(float* __restrict__ theta,
                                                          unsigned short* __restrict__ Xt,
                                                          const float* __restrict__ P,
                                                          const float* __restrict__ omega,
                                                          const float* __restrict__ Kg,
                                                          const float* __restrict__ mu) {
    __shared__ float Ts[UPD_I][68];          // 16B-aligned rows, <=2-way banks

    const int tid = threadIdx.x;
    const int iBase = blockIdx.x * UPD_I;

    // ---- phase 1: thread -> (i_local = tid>>4, c-quad = tid&15)
    {
        const int il = tid >> 4;
        const int c4 = (tid & 15) * 4;
        const float* Pp = P + ((size_t)iBase + il) * COLS + c4;
        float4 a = {0.f, 0.f, 0.f, 0.f};
#pragma unroll
        for (int ss = 0; ss < JS; ++ss) {
            float4 v = *(const float4*)(Pp + (size_t)ss * NN * COLS);
            a.x += v.x; a.y += v.y; a.z += v.z; a.w += v.w;
        }
        *(float4*)&Ts[il][c4] = a;
    }
    __syncthreads();

    // ---- phase 2
    const float g = (Kg[0] / (float)NN) * (mu[0] * 0.5f);
    const int il = tid & 15;
    const int b0 = tid >> 4;
    const int i  = iBase + il;
    const float om = omega[i];
#pragma unroll
    for (int k = 0; k < 2; ++k) {
        const int b = b0 + k * 16;
        float sumS = Ts[il][b];
        float sumC = Ts[il][32 + b];
        float th = theta[(size_t)b * NN + i];
        float sV = sinf(th);
        float cV = cosf(th);

        float dth = om + g * (cV * sumS - sV * sumC);
        float thn = th + DT_STEP * dth;
        float sn = sinf(thn);
        float cn = cosf(thn);
        theta[(size_t)b * NN + i] = atan2f(sn, cn);
        Xt[(size_t)b * NN + i]        = f2bf(sn);
        Xt[(size_t)(32 + b) * NN + i] = f2bf(cn);
    }
}

// ---------------------------------------------------------------------------
// coherence
// ---------------------------------------------------------------------------
__global__ __launch_bounds__(256) void coh_kernel(const float* __restrict__ theta,
                                                  float* __restrict__ out) {
    int b = blockIdx.x;
    const float* th = theta + (size_t)b * NN;
    float sc = 0.f, ss = 0.f;
    for (int i = threadIdx.x; i < NN; i += 256) {
        float t = th[i];
        sc += cosf(t);
        ss += sinf(t);
    }
    for (int off = 32; off > 0; off >>= 1) {
        sc += __shfl_down(sc, off);
        ss += __shfl_down(ss, off);
    }
    __shared__ float red[2][4];
    int wave = threadIdx.x >> 6;
    if ((threadIdx.x & 63) == 0) { red[0][wave] = sc; red[1][wave] = ss; }
    __syncthreads();
    if (threadIdx.x == 0) {
        float csum = red[0][0] + red[0][1] + red[0][2] + red[0][3];
        float ssum = red[1][0] + red[1][1] + red[1][2] + red[1][3];
        float cm = csum / (float)NN;
        float sm = ssum / (float)NN;
        out[b] = sqrtf(cm * cm + sm * sm);
    }
}

extern "C" void kernel_launch(void* const* d_in, const int* in_sizes, int n_in,
                              void* d_out, int out_size, void* d_ws, size_t ws_size,
                              hipStream_t stream) {
    const float* theta0 = (const float*)d_in[0];
    const float* K      = (const float*)d_in[1];
    const float* omega  = (const float*)d_in[2];
    const float* Kg     = (const float*)d_in[3];
    const float* mu     = (const float*)d_in[4];

    float* out   = (float*)d_out;
    float* theta = out;                 // BATCH*NN
    float* coh   = out + BATCH * NN;    // BATCH

    unsigned short* Kb = (unsigned short*)d_ws;     // NN*NN bf16   (8.4 MB)
    unsigned short* Xt = Kb + (size_t)NN * NN;      // 64 x NN bf16 (256 KB)
    float* P = (float*)(Xt + (size_t)COLS * NN);    // JS x NN x COLS fp32 (8.4 MB)

    prep_kernel<<<(NN * NN / 8) / 256, 256, 0, stream>>>(theta0, K, theta, Xt, Kb);
    for (int step = 0; step < NSTEPS; ++step) {
        gemm_mfma_kernel<<<GRID_SZ, 256, 0, stream>>>(Kb, Xt, P);
        update_step_kernel<<<UPD_GRID, 256, 0, stream>>>(theta, Xt, P, omega, Kg, mu);
    }
    coh_kernel<<<BATCH, 256, 0, stream>>>(theta, coh);
}

// Round 11
// 159.860 us; speedup vs baseline: 7.0508x; 1.3672x over previous
//
#include <hip/hip_runtime.h>
#include <math.h>

#define NN 2048
#define BATCH 32
#define COLS 64
#define DT_STEP 0.1f
#define NSTEPS 10

typedef __attribute__((ext_vector_type(8))) short bf16x8;   // 8 bf16 (4 VGPRs)
typedef __attribute__((ext_vector_type(4))) float f32x4;

// RNE float -> bf16
__device__ __forceinline__ unsigned short f2bf(float f) {
    unsigned int u = __float_as_uint(f);
    u += 0x7FFFu + ((u >> 16) & 1u);
    return (unsigned short)(u >> 16);
}
__device__ __forceinline__ unsigned int pk2(float a, float b) {
    return (unsigned int)f2bf(a) | ((unsigned int)f2bf(b) << 16);
}

// ---------------------------------------------------------------------------
// prep: K fp32 -> bf16 (every call: ws re-poisoned), theta copy,
// Xt[c][j] bf16 (c<32: sin(theta[c]); c>=32: cos(theta[c-32])).
// ---------------------------------------------------------------------------
__global__ __launch_bounds__(256) void prep_kernel(const float* __restrict__ theta_in,
                                                   const float* __restrict__ K,
                                                   float* __restrict__ theta,
                                                   unsigned short* __restrict__ Xt,
                                                   unsigned short* __restrict__ Kb) {
    int t = blockIdx.x * 256 + threadIdx.x;          // 0 .. 524287
    {
        const float4* K4 = (const float4*)K;
        float4 v0 = K4[2 * t];
        float4 v1 = K4[2 * t + 1];
        uint4 o;
        o.x = pk2(v0.x, v0.y);
        o.y = pk2(v0.z, v0.w);
        o.z = pk2(v1.x, v1.y);
        o.w = pk2(v1.z, v1.w);
        ((uint4*)Kb)[t] = o;
    }
    if (t < BATCH * NN) {
        int b = t >> 11;
        int i = t & (NN - 1);
        float th = theta_in[t];
        theta[t] = th;
        Xt[(size_t)b * NN + i]        = f2bf(sinf(th));
        Xt[(size_t)(32 + b) * NN + i] = f2bf(cosf(th));
    }
}

// ---------------------------------------------------------------------------
// monolithic step: block (h, rb) owns output tile rows i0..i0+15 x batches
// h*16..h*16+15, FULL K=2048. Wave w: K-chunk [w*512,(w+1)*512), two MFMA
// accumulators (S-cols = batch, C-cols = 32+batch). 4-wave LDS reduce, then
// fused Kuramoto update for the tile. No split-K buffer, no 2nd kernel.
// A frag: lane l -> Kb[i0 + (l&15)][k0 + kc*32 + (l>>4)*8 + e]
// B frag: lane l -> Xt[c0 + (l&15)][same k]     (c0 = h*16 or 32+h*16)
// D:      row(i-local) = (l>>4)*4 + r, col(c-local) = l&15   [r10-verified]
// ---------------------------------------------------------------------------
__global__ __launch_bounds__(256) void step_kernel(const unsigned short* __restrict__ Kb,
                                                   float* __restrict__ theta,
                                                   unsigned short* __restrict__ Xt,
                                                   const float* __restrict__ omega,
                                                   const float* __restrict__ Kg,
                                                   const float* __restrict__ mu) {
    __shared__ float red[4][2][16][16];   // [wave][S/C][c-local][i-local] = 8 KB

    const int tid = threadIdx.x;
    const int bid = blockIdx.x;
    const int h  = bid >> 7;              // batch half 0/1
    const int rb = bid & 127;             // row block; bid%8 == rb%8 both halves
    const int w  = tid >> 6;
    const int l  = tid & 63;
    const int lr = l & 15;
    const int lk = l >> 4;                // 0..3
    const int i0 = rb * 16;
    const int k0 = w * 512;

    const unsigned short* Ap  = Kb + (size_t)(i0 + lr) * NN + k0 + lk * 8;
    const unsigned short* BpS = Xt + (size_t)(h * 16 + lr) * NN + k0 + lk * 8;
    const unsigned short* BpC = BpS + (size_t)32 * NN;

    f32x4 accS = {0.f, 0.f, 0.f, 0.f};
    f32x4 accC = {0.f, 0.f, 0.f, 0.f};

#pragma unroll
    for (int kc = 0; kc < 16; ++kc) {
        bf16x8 a  = *(const bf16x8*)(Ap  + kc * 32);
        bf16x8 bS = *(const bf16x8*)(BpS + kc * 32);
        bf16x8 bC = *(const bf16x8*)(BpC + kc * 32);
        accS = __builtin_amdgcn_mfma_f32_16x16x32_bf16(a, bS, accS, 0, 0, 0);
        accC = __builtin_amdgcn_mfma_f32_16x16x32_bf16(a, bC, accC, 0, 0, 0);
    }

    // partials -> LDS: red[w][sc][lr][lk*4 + r]  (16B-aligned float4 stores)
    *(f32x4*)&red[w][0][lr][lk * 4] = accS;
    *(f32x4*)&red[w][1][lr][lk * 4] = accC;
    __syncthreads();

    // tail: thread t -> (il = t&15 fast -> coalesced i, j = t>>4 batch-local)
    const int il = tid & 15;
    const int j  = tid >> 4;
    float sumS = red[0][0][j][il] + red[1][0][j][il]
               + red[2][0][j][il] + red[3][0][j][il];
    float sumC = red[0][1][j][il] + red[1][1][j][il]
               + red[2][1][j][il] + red[3][1][j][il];

    const float g = (Kg[0] / (float)NN) * (mu[0] * 0.5f);
    const int i = i0 + il;
    const int b = h * 16 + j;
    float th = theta[(size_t)b * NN + i];
    float sV = sinf(th);
    float cV = cosf(th);
    float dth = omega[i] + g * (cV * sumS - sV * sumC);
    float thn = th + DT_STEP * dth;
    float sn = sinf(thn);
    float cn = cosf(thn);
    theta[(size_t)b * NN + i] = atan2f(sn, cn);
    Xt[(size_t)b * NN + i]        = f2bf(sn);
    Xt[(size_t)(32 + b) * NN + i] = f2bf(cn);
}

// ---------------------------------------------------------------------------
// coherence
// ---------------------------------------------------------------------------
__global__ __launch_bounds__(256) void coh_kernel(const float* __restrict__ theta,
                                                  float* __restrict__ out) {
    int b = blockIdx.x;
    const float* th = theta + (size_t)b * NN;
    float sc = 0.f, ss = 0.f;
    for (int i = threadIdx.x; i < NN; i += 256) {
        float t = th[i];
        sc += cosf(t);
        ss += sinf(t);
    }
    for (int off = 32; off > 0; off >>= 1) {
        sc += __shfl_down(sc, off);
        ss += __shfl_down(ss, off);
    }
    __shared__ float red[2][4];
    int wave = threadIdx.x >> 6;
    if ((threadIdx.x & 63) == 0) { red[0][wave] = sc; red[1][wave] = ss; }
    __syncthreads();
    if (threadIdx.x == 0) {
        float csum = red[0][0] + red[0][1] + red[0][2] + red[0][3];
        float ssum = red[1][0] + red[1][1] + red[1][2] + red[1][3];
        float cm = csum / (float)NN;
        float sm = ssum / (float)NN;
        out[b] = sqrtf(cm * cm + sm * sm);
    }
}

extern "C" void kernel_launch(void* const* d_in, const int* in_sizes, int n_in,
                              void* d_out, int out_size, void* d_ws, size_t ws_size,
                              hipStream_t stream) {
    const float* theta0 = (const float*)d_in[0];
    const float* K      = (const float*)d_in[1];
    const float* omega  = (const float*)d_in[2];
    const float* Kg     = (const float*)d_in[3];
    const float* mu     = (const float*)d_in[4];

    float* out   = (float*)d_out;
    float* theta = out;                 // BATCH*NN
    float* coh   = out + BATCH * NN;    // BATCH

    unsigned short* Kb = (unsigned short*)d_ws;     // NN*NN bf16   (8.4 MB)
    unsigned short* Xt = Kb + (size_t)NN * NN;      // 64 x NN bf16 (256 KB)

    prep_kernel<<<(NN * NN / 8) / 256, 256, 0, stream>>>(theta0, K, theta, Xt, Kb);
    for (int step = 0; step < NSTEPS; ++step) {
        step_kernel<<<256, 256, 0, stream>>>(Kb, theta, Xt, omega, Kg, mu);
    }
    coh_kernel<<<BATCH, 256, 0, stream>>>(theta, coh);
}

// Round 13
// 149.851 us; speedup vs baseline: 7.5218x; 1.0668x over previous
//
#include <hip/hip_runtime.h>
#include <math.h>

#define NN 2048
#define BATCH 32
#define COLS 64
#define DT_STEP 0.1f
#define NSTEPS 10

typedef __attribute__((ext_vector_type(8))) short bf16x8;   // 8 bf16 (4 VGPRs)
typedef __attribute__((ext_vector_type(4))) float f32x4;

// RNE float -> bf16
__device__ __forceinline__ unsigned short f2bf(float f) {
    unsigned int u = __float_as_uint(f);
    u += 0x7FFFu + ((u >> 16) & 1u);
    return (unsigned short)(u >> 16);
}
__device__ __forceinline__ unsigned int pk2(float a, float b) {
    return (unsigned int)f2bf(a) | ((unsigned int)f2bf(b) << 16);
}

// ---------------------------------------------------------------------------
// prep: K fp32 -> bf16 in MFMA-A-fragment-tiled order:
//   Kt linear index ((rb*64 + c)*64 + l)*8 + e  <-  K[rb*16 + (l&15)][c*32 + (l>>4)*8 + e]
// so a wave's A-frag load for (rb, chunk c) is ONE contiguous 1024 B stream.
// Also: theta copy + Xt[col][j] bf16 init (col<32: sin; col>=32: cos).
// Runs every call (ws re-poisoned by harness).
// ---------------------------------------------------------------------------
__global__ __launch_bounds__(256) void prep_kernel(const float* __restrict__ theta_in,
                                                   const float* __restrict__ K,
                                                   float* __restrict__ theta,
                                                   unsigned short* __restrict__ Xt,
                                                   unsigned short* __restrict__ Kt) {
    int t = blockIdx.x * 256 + threadIdx.x;          // 0 .. 524287 (8 elems each)
    {
        const int rb = t >> 12;                      // 0..127
        const int c  = (t >> 6) & 63;                // 0..63 k-chunk
        const int l  = t & 63;                       // lane slot
        const int lr = l & 15;
        const int lk = l >> 4;
        const float* src = K + (size_t)(rb * 16 + lr) * NN + c * 32 + lk * 8;
        float4 v0 = *(const float4*)(src);
        float4 v1 = *(const float4*)(src + 4);
        uint4 o;
        o.x = pk2(v0.x, v0.y);
        o.y = pk2(v0.z, v0.w);
        o.z = pk2(v1.x, v1.y);
        o.w = pk2(v1.z, v1.w);
        ((uint4*)Kt)[t] = o;
    }
    if (t < BATCH * NN) {
        int b = t >> 11;
        int i = t & (NN - 1);
        float th = theta_in[t];
        theta[t] = th;
        Xt[(size_t)b * NN + i]        = f2bf(sinf(th));
        Xt[(size_t)(32 + b) * NN + i] = f2bf(cosf(th));
    }
}

// ---------------------------------------------------------------------------
// monolithic step: block (h, rb) owns rows i0..i0+15 x batches h*16..+15,
// FULL K=2048. 8 waves (512 thr): wave w sweeps k-chunk [w*256,(w+1)*256)
// -> 2 waves/SIMD (r11 ran 1/SIMD: latency-exposed). 8-way LDS reduce,
// then fused Kuramoto tail on threads 0..255.
// A frag (tiled): Kt[rb*32768 + (w*8+kc)*512 + l*8 + e]
//               == K[i0+(l&15)][w*256 + kc*32 + (l>>4)*8 + e]   (r11-verified)
// B frag: Xt[c0+(l&15)][w*256 + kc*32 + (l>>4)*8 + e]
// D: row(i-local) = (l>>4)*4 + r, col = l&15                    (r10-verified)
// ---------------------------------------------------------------------------
__global__ __launch_bounds__(512) void step_kernel(const unsigned short* __restrict__ Kt,
                                                   float* __restrict__ theta,
                                                   unsigned short* __restrict__ Xt,
                                                   const float* __restrict__ omega,
                                                   const float* __restrict__ Kg,
                                                   const float* __restrict__ mu) {
    __shared__ float red[8][2][16][16];   // [wave][S/C][c-local][i-local] = 16 KB

    const int tid = threadIdx.x;
    const int bid = blockIdx.x;
    const int h  = bid >> 7;              // batch half 0/1
    const int rb = bid & 127;             // row block (bid%8 XCD-stable)
    const int w  = tid >> 6;              // 0..7
    const int l  = tid & 63;
    const int lr = l & 15;
    const int lk = l >> 4;
    const int i0 = rb * 16;
    const int k0 = w * 256;

    const unsigned short* Ap  = Kt + (size_t)rb * 32768 + (size_t)w * 8 * 512 + l * 8;
    const unsigned short* BpS = Xt + (size_t)(h * 16 + lr) * NN + k0 + lk * 8;
    const unsigned short* BpC = BpS + (size_t)32 * NN;

    f32x4 accS = {0.f, 0.f, 0.f, 0.f};
    f32x4 accC = {0.f, 0.f, 0.f, 0.f};

#pragma unroll
    for (int kc = 0; kc < 8; ++kc) {
        bf16x8 a  = *(const bf16x8*)(Ap  + kc * 512);   // contiguous 1KB/wave
        bf16x8 bS = *(const bf16x8*)(BpS + kc * 32);
        bf16x8 bC = *(const bf16x8*)(BpC + kc * 32);
        accS = __builtin_amdgcn_mfma_f32_16x16x32_bf16(a, bS, accS, 0, 0, 0);
        accC = __builtin_amdgcn_mfma_f32_16x16x32_bf16(a, bC, accC, 0, 0, 0);
    }

    *(f32x4*)&red[w][0][lr][lk * 4] = accS;
    *(f32x4*)&red[w][1][lr][lk * 4] = accC;
    __syncthreads();

    if (tid < 256) {
        const int il = tid & 15;          // i-local (fast -> coalesced)
        const int j  = tid >> 4;          // batch-local
        float sumS = 0.f, sumC = 0.f;
#pragma unroll
        for (int ww = 0; ww < 8; ++ww) {
            sumS += red[ww][0][j][il];
            sumC += red[ww][1][j][il];
        }

        const float g = (Kg[0] / (float)NN) * (mu[0] * 0.5f);
        const int i = i0 + il;
        const int b = h * 16 + j;
        float th = theta[(size_t)b * NN + i];
        float sV = sinf(th);
        float cV = cosf(th);
        float dth = omega[i] + g * (cV * sumS - sV * sumC);
        float thn = th + DT_STEP * dth;
        float sn = sinf(thn);
        float cn = cosf(thn);
        theta[(size_t)b * NN + i] = atan2f(sn, cn);
        Xt[(size_t)b * NN + i]        = f2bf(sn);
        Xt[(size_t)(32 + b) * NN + i] = f2bf(cn);
    }
}

// ---------------------------------------------------------------------------
// coherence
// ---------------------------------------------------------------------------
__global__ __launch_bounds__(256) void coh_kernel(const float* __restrict__ theta,
                                                  float* __restrict__ out) {
    int b = blockIdx.x;
    const float* th = theta + (size_t)b * NN;
    float sc = 0.f, ss = 0.f;
    for (int i = threadIdx.x; i < NN; i += 256) {
        float t = th[i];
        sc += cosf(t);
        ss += sinf(t);
    }
    for (int off = 32; off > 0; off >>= 1) {
        sc += __shfl_down(sc, off);
        ss += __shfl_down(ss, off);
    }
    __shared__ float red[2][4];
    int wave = threadIdx.x >> 6;
    if ((threadIdx.x & 63) == 0) { red[0][wave] = sc; red[1][wave] = ss; }
    __syncthreads();
    if (threadIdx.x == 0) {
        float csum = red[0][0] + red[0][1] + red[0][2] + red[0][3];
        float ssum = red[1][0] + red[1][1] + red[1][2] + red[1][3];
        float cm = csum / (float)NN;
        float sm = ssum / (float)NN;
        out[b] = sqrtf(cm * cm + sm * sm);
    }
}

extern "C" void kernel_launch(void* const* d_in, const int* in_sizes, int n_in,
                              void* d_out, int out_size, void* d_ws, size_t ws_size,
                              hipStream_t stream) {
    const float* theta0 = (const float*)d_in[0];
    const float* K      = (const float*)d_in[1];
    const float* omega  = (const float*)d_in[2];
    const float* Kg     = (const float*)d_in[3];
    const float* mu     = (const float*)d_in[4];

    float* out   = (float*)d_out;
    float* theta = out;                 // BATCH*NN
    float* coh   = out + BATCH * NN;    // BATCH

    unsigned short* Kt = (unsigned short*)d_ws;     // NN*NN bf16 tiled (8.4 MB)
    unsigned short* Xt = Kt + (size_t)NN * NN;      // 64 x NN bf16     (256 KB)

    prep_kernel<<<(NN * NN / 8) / 256, 256, 0, stream>>>(theta0, K, theta, Xt, Kt);
    for (int step = 0; step < NSTEPS; ++step) {
        step_kernel<<<256, 512, 0, stream>>>(Kt, theta, Xt, omega, Kg, mu);
    }
    coh_kernel<<<BATCH, 256, 0, stream>>>(theta, coh);
}